// Round 9
// baseline (182.483 us; speedup 1.0000x reference)
//
#include <hip/hip_runtime.h>
#include <cstdint>
#include <cstddef>

// MHA fused pipeline for B=2,S=2048,D=1024,H=16,DK=64 on gfx950.
// bf16 MFMA (16x16x32) with fp32 accum; V = Q (reference bug replicated).
// R9 = R7 with pk2bf reverted to pure-integer packing (__hip_bfloat162 is not
// trivially copyable -> __builtin_bit_cast rejected it; R8 compile failure).
// R7 content: separate LDS-tiled transpose_q (fused-qT epilogue was
// write-amplified), Ps padded to 144B rows, hoisted staging pointers.

#define AS1 __attribute__((address_space(1)))
#define AS3 __attribute__((address_space(3)))

typedef unsigned short u16;
typedef __attribute__((ext_vector_type(8))) short bf16x8;  // 8 bf16 (4 VGPRs)
typedef __attribute__((ext_vector_type(4))) float f32x4;

__device__ __forceinline__ u16 f2bf(float f) {
  uint32_t u = __builtin_bit_cast(uint32_t, f);
  u += 0x7fffu + ((u >> 16) & 1u);   // RNE
  return (u16)(u >> 16);
}
__device__ __forceinline__ uint32_t pk2bf(float a, float b) {
  return (uint32_t)f2bf(a) | ((uint32_t)f2bf(b) << 16);
}

// async global->LDS, 16B per lane. LDS dest is wave-uniform base + lane*16.
__device__ __forceinline__ void gload16(const void* g, void* l) {
  __builtin_amdgcn_global_load_lds((const AS1 uint32_t*)(uintptr_t)g,
                                   (AS3 uint32_t*)(uintptr_t)l, 16, 0, 0);
}

#define SCALE2 0.18033688011112042f   // (1/8) * log2(e)

// ------- prep: cvt x (blocks 0..1023) + transpose weights (blocks 1024..1791) ----
__global__ __launch_bounds__(256) void prep_kernel(
    const float* __restrict__ x, u16* __restrict__ xb,
    const float* __restrict__ Wq, const float* __restrict__ Wk,
    const float* __restrict__ W0, u16* __restrict__ wqT,
    u16* __restrict__ wkT, u16* __restrict__ w0T) {
  __shared__ u16 T[64][65];
  const int bid = blockIdx.x;
  if (bid < 1024) {
    const float4* x4 = (const float4*)x;
    ushort4* o4 = (ushort4*)xb;
    for (int i = bid * 256 + threadIdx.x; i < 1048576; i += 262144) {
      float4 v = x4[i];
      ushort4 o;
      o.x = f2bf(v.x); o.y = f2bf(v.y); o.z = f2bf(v.z); o.w = f2bf(v.w);
      o4[i] = o;
    }
    return;
  }
  const int t = bid - 1024;
  const int z = t >> 8, y = (t >> 4) & 15, xt = t & 15;
  const float* src; u16* dst;
  if (z == 0)      { src = Wq; dst = wqT; }
  else if (z == 1) { src = Wk; dst = wkT; }
  else             { src = W0; dst = w0T; }
  const int k0 = y * 64, n0 = xt * 64;
  const int c = threadIdx.x & 63, r0 = threadIdx.x >> 6;
#pragma unroll
  for (int i = 0; i < 16; ++i) {
    int r = i * 4 + r0;
    T[r][c] = f2bf(src[(size_t)(k0 + r) * 1024 + n0 + c]);
  }
  __syncthreads();
#pragma unroll
  for (int i = 0; i < 16; ++i) {
    int r = i * 4 + r0;
    dst[(size_t)(n0 + r) * 1024 + k0 + c] = T[c][r];  // WT[n][k] = W[k][n]
  }
}

// ------- transpose q: [BH][S][64] -> qT [BH][64][S] (bf16, LDS-tiled) -------
__global__ __launch_bounds__(256) void transpose_q_kernel(const u16* __restrict__ q,
                                                          u16* __restrict__ qT) {
  const int bh = blockIdx.y;
  const int s0 = blockIdx.x * 64;
  const u16* src = q + (size_t)bh * 2048 * 64;
  u16* dst = qT + (size_t)bh * 64 * 2048;
  __shared__ u16 T[64][65];
  const int c = threadIdx.x & 63, r0 = threadIdx.x >> 6;
#pragma unroll
  for (int i = 0; i < 16; ++i) {
    int r = i * 4 + r0;
    T[r][c] = src[(size_t)(s0 + r) * 64 + c];
  }
  __syncthreads();
#pragma unroll
  for (int i = 0; i < 16; ++i) {
    int r = i * 4 + r0;
    dst[(size_t)r * 2048 + s0 + c] = T[c][r];  // qT[d][s] = q[s][d]
  }
}

// ------- GEMM: C[4096][N] = A @ BT^T + bias. 128x128 tile, 8 waves, BK=64. ----
// EPI 0 (fused QK proj, NTILES=16): n<1024 -> q (bf16 head layout, +bq);
//   n>=1024 -> k (bf16 head layout, (acc+bk)*SCALE2 pre-scaled).
// EPI 2 (out proj, NTILES=8): fp32 row-major +bias0.
template <int EPI, int NTILES>
__global__ __launch_bounds__(512, 4) void gemm_kernel(
    const u16* __restrict__ A, const u16* __restrict__ BT,
    const float* __restrict__ bias0, const float* __restrict__ bias1,
    u16* __restrict__ Oq, u16* __restrict__ Ok, float* __restrict__ Of) {
  __shared__ __align__(16) u16 As[128][64];
  __shared__ __align__(16) u16 Bs[128][64];
  const int tid = threadIdx.x, wid = tid >> 6, lane = tid & 63;
  const int l15 = lane & 15, lg = lane >> 4;
  constexpr int NH = NTILES / 2;
  const int bid = blockIdx.x;
  const int c = bid & 7, l = bid >> 3;
  const int m0 = ((c >> 1) * 8 + l / NH) * 128;
  const int n0 = ((c & 1) * NH + l % NH) * 128;
  const int wrow = (wid >> 2) * 64, wcol = (wid & 3) * 32;
  const int srow = lane >> 3;
  const int gz = ((lane & 7) ^ srow) * 8;   // pre-swizzled global col (u16)

  f32x4 acc[4][2] = {};

  for (int k0 = 0; k0 < 1024; k0 += 64) {
#pragma unroll
    for (int i = 0; i < 2; ++i) {
      int ch = wid * 2 + i;  // 16 chunks of 8 rows each, for both tiles
      gload16(&A[(size_t)(m0 + ch * 8 + srow) * 1024 + k0 + gz], &As[ch * 8][0]);
      gload16(&BT[(size_t)(n0 + ch * 8 + srow) * 1024 + k0 + gz], &Bs[ch * 8][0]);
    }
    __syncthreads();
#pragma unroll
    for (int kf = 0; kf < 2; ++kf) {
      const int cg = ((kf * 4 + lg) ^ (lane & 7)) * 8;  // swizzled read granule
      bf16x8 af[4], bfr[2];
#pragma unroll
      for (int m = 0; m < 4; ++m)
        af[m] = *(const bf16x8*)&As[wrow + m * 16 + l15][cg];
#pragma unroll
      for (int n = 0; n < 2; ++n)
        bfr[n] = *(const bf16x8*)&Bs[wcol + n * 16 + l15][cg];
#pragma unroll
      for (int m = 0; m < 4; ++m)
#pragma unroll
        for (int n = 0; n < 2; ++n)
          acc[m][n] = __builtin_amdgcn_mfma_f32_16x16x32_bf16(af[m], bfr[n], acc[m][n], 0, 0, 0);
    }
    __syncthreads();
  }

  // epilogue
  const bool isq = (n0 < 1024);  // block-uniform (tiles are 128-wide)
  float bv[2];
#pragma unroll
  for (int n = 0; n < 2; ++n) {
    const int gn = n0 + wcol + n * 16 + l15;
    if constexpr (EPI == 0)
      bv[n] = isq ? bias0[gn] : bias1[gn - 1024];
    else
      bv[n] = bias0[gn];
  }
#pragma unroll
  for (int m = 0; m < 4; ++m) {
#pragma unroll
    for (int r = 0; r < 4; ++r) {
      const int gm = m0 + wrow + m * 16 + lg * 4 + r;
#pragma unroll
      for (int n = 0; n < 2; ++n) {
        const int gn = n0 + wcol + n * 16 + l15;
        float v = acc[m][n][r] + bv[n];
        if constexpr (EPI == 2) {
          Of[(size_t)gm * 1024 + gn] = v;
        } else {
          const int gg = gn & 1023;
          const int b = gm >> 11, s = gm & 2047;
          const int h = gg >> 6, dk = gg & 63;
          const size_t bh = (size_t)(b * 16 + h);
          if (isq) {
            Oq[(bh * 2048 + s) * 64 + dk] = f2bf(v);
          } else {
            Ok[(bh * 2048 + s) * 64 + dk] = f2bf(v * SCALE2);  // pre-scaled K
          }
        }
      }
    }
  }
}

// ---------------- flash attention, causal, V = Q, swapped QK^T ----------------
// 1024 blocks (1 q-tile each), heavy-first; bh = bid&31 -> XCD-affine.
// 4 waves x 16 q-rows. Each lane owns q-row l15: S^T accum has kv lane-local.
__global__ __launch_bounds__(256, 4) void attn_kernel(const u16* __restrict__ Q,
                                                      const u16* __restrict__ K,
                                                      const u16* __restrict__ QT,
                                                      u16* __restrict__ ATT) {
  __shared__ __align__(16) u16 Ks[2][64][64];    // K tile  [kv][dk]   (swizzled)
  __shared__ __align__(16) u16 Vs[2][64][64];    // V^T tile [dk][kv]  (swizzled)
  __shared__ __align__(16) u16 Ps[4][16][72];    // per-wave P [q][kv], 144B rows
  const int tid = threadIdx.x, wid = tid >> 6, lane = tid & 63;
  const int l15 = lane & 15, lg = lane >> 4;
  const int bid = blockIdx.x;
  const int bh = bid & 31;              // bid%8 spreads bh across XCDs
  const int qt = 31 - (bid >> 5);       // heavy tiles dispatched first
  const size_t base = (size_t)bh * 2048 * 64;
  const int bb = bh >> 4, hh = bh & 15;
  const int srow = lane >> 3;
  const int gz = ((lane & 7) ^ srow) * 8;

  const int q0 = qt * 64;
  const int wrow = q0 + wid * 16;

  // hoisted staging pointers (this thread's two chunk rows of each tile)
  const u16* kA  = K  + base + (size_t)(wid * 16 + srow) * 64 + gz;        // +t*4096
  const u16* kB  = kA + 8 * 64;
  const u16* vA  = QT + base + (size_t)(wid * 16 + srow) * 2048 + gz;      // +t*64
  const u16* vB  = vA + 8 * 2048;
  u16* ldsKA = &Ks[0][wid * 16][0];      // buffer stride = 64*64 u16
  u16* ldsKB = &Ks[0][wid * 16 + 8][0];
  u16* ldsVA = &Vs[0][wid * 16][0];
  u16* ldsVB = &Vs[0][wid * 16 + 8][0];
  const int bufo = 64 * 64;              // u16 per buffer

  bf16x8 qf[2];   // Q rows for this wave: row = wrow + l15 (B-operand fragment)
#pragma unroll
  for (int kf = 0; kf < 2; ++kf)
    qf[kf] = *(const bf16x8*)&Q[base + (size_t)(wrow + l15) * 64 + kf * 32 + lg * 8];

  f32x4 o[4] = {};          // O^T accum: o[m][r] = O^T[d=m*16+lg*4+r][q=l15]
  float mx = -3e38f, sm = 0.f;

  // prologue: stage tile 0 into buffer 0
  gload16(kA, ldsKA); gload16(kB, ldsKB);
  gload16(vA, ldsVA); gload16(vB, ldsVB);
  __syncthreads();

  for (int t = 0; t <= qt; ++t) {
    const int cur = t & 1;
    if (t < qt) {           // prefetch next tile into the other buffer
      const int nxt = (cur ^ 1) * bufo;
      gload16(kA + (t + 1) * 4096, ldsKA + nxt);
      gload16(kB + (t + 1) * 4096, ldsKB + nxt);
      gload16(vA + (t + 1) * 64,   ldsVA + nxt);
      gload16(vB + (t + 1) * 64,   ldsVB + nxt);
    }

    // S^T = K Q^T  (rows kv = n*16+lg*4+r, cols q = l15). K pre-scaled to log2.
    f32x4 sc[4] = {};
#pragma unroll
    for (int kf = 0; kf < 2; ++kf) {
      const int cg = ((kf * 4 + lg) ^ (lane & 7)) * 8;
      bf16x8 kb[4];
#pragma unroll
      for (int n = 0; n < 4; ++n)
        kb[n] = *(const bf16x8*)&Ks[cur][n * 16 + l15][cg];
      __builtin_amdgcn_s_setprio(1);
#pragma unroll
      for (int n = 0; n < 4; ++n)
        sc[n] = __builtin_amdgcn_mfma_f32_16x16x32_bf16(kb[n], qf[kf], sc[n], 0, 0, 0);
      __builtin_amdgcn_s_setprio(0);
    }

    // causal mask on diagonal tile: kv (= n*16+lg*4+r) > q (= wid*16+l15)
    if (t == qt) {
      const int qq = wid * 16 + l15;
#pragma unroll
      for (int n = 0; n < 4; ++n)
#pragma unroll
        for (int r = 0; r < 4; ++r)
          if (n * 16 + lg * 4 + r > qq) sc[n][r] = -1e30f;
    }

    // row max: in-register tree over this lane's 16 kv values + 2 shfl (lg groups)
    float ma = fmaxf(fmaxf(sc[0][0], sc[0][1]), fmaxf(sc[0][2], sc[0][3]));
    float mb = fmaxf(fmaxf(sc[1][0], sc[1][1]), fmaxf(sc[1][2], sc[1][3]));
    float mc = fmaxf(fmaxf(sc[2][0], sc[2][1]), fmaxf(sc[2][2], sc[2][3]));
    float md = fmaxf(fmaxf(sc[3][0], sc[3][1]), fmaxf(sc[3][2], sc[3][3]));
    float rmax = fmaxf(fmaxf(ma, mb), fmaxf(mc, md));
    rmax = fmaxf(rmax, __shfl_xor(rmax, 16));
    rmax = fmaxf(rmax, __shfl_xor(rmax, 32));

    // defer-max (T13): rescale only when max grew by >8 (log2 units)
    if (__any(rmax > mx + 8.0f)) {
      const float mnew = fmaxf(mx, rmax);
      const float alpha = exp2f(mx - mnew);
      mx = mnew;
      sm *= alpha;
#pragma unroll
      for (int m = 0; m < 4; ++m) o[m] *= alpha;
    }

    // exp2, partial sum (per-lane), pack to bf16
    float psum = 0.f;
    uint32_t w[4][2];
#pragma unroll
    for (int n = 0; n < 4; ++n) {
      const float p0 = exp2f(sc[n][0] - mx), p1 = exp2f(sc[n][1] - mx);
      const float p2 = exp2f(sc[n][2] - mx), p3 = exp2f(sc[n][3] - mx);
      psum += (p0 + p1) + (p2 + p3);
      w[n][0] = pk2bf(p0, p1);
      w[n][1] = pk2bf(p2, p3);
    }
    sm += psum;

    // P -> LDS as [q=l15][kv], kv-run of 4 per store -> ds_write_b64, swizzled
#pragma unroll
    for (int n = 0; n < 4; ++n) {
      const int col = (((2 * n + (lg >> 1)) ^ (l15 & 7)) << 3) + ((lg & 1) << 2);
      uint2 wv; wv.x = w[n][0]; wv.y = w[n][1];
      *(uint2*)&Ps[wid][l15][col] = wv;
    }
    asm volatile("s_waitcnt lgkmcnt(0)" ::: "memory");

    // O^T += V^T P^T   (A = V^T rows d, B = P^T cols q)
#pragma unroll
    for (int kf = 0; kf < 2; ++kf) {
      const int cg = ((kf * 4 + lg) ^ (lane & 7)) * 8;
      bf16x8 pb = *(const bf16x8*)&Ps[wid][l15][cg];
      bf16x8 vb[4];
#pragma unroll
      for (int m = 0; m < 4; ++m)
        vb[m] = *(const bf16x8*)&Vs[cur][m * 16 + l15][cg];
      __builtin_amdgcn_s_setprio(1);
#pragma unroll
      for (int m = 0; m < 4; ++m)
        o[m] = __builtin_amdgcn_mfma_f32_16x16x32_bf16(vb[m], pb, o[m], 0, 0, 0);
      __builtin_amdgcn_s_setprio(0);
    }
    __syncthreads();   // drains prefetch vmcnt + LDS; next iter reads other buffer
  }

  // final sum reduce over the 4 lg-lanes sharing q-row l15
  sm += __shfl_xor(sm, 16);
  sm += __shfl_xor(sm, 32);
  const float inv = 1.0f / sm;
  const int s = wrow + l15;
#pragma unroll
  for (int m = 0; m < 4; ++m) {
    uint2 wv;
    wv.x = pk2bf(o[m][0] * inv, o[m][1] * inv);
    wv.y = pk2bf(o[m][2] * inv, o[m][3] * inv);
    *(uint2*)&ATT[((size_t)(bb * 2048 + s)) * 1024 + hh * 64 + m * 16 + lg * 4] = wv;
  }
}

// ---------------- launcher ----------------
extern "C" void kernel_launch(void* const* d_in, const int* in_sizes, int n_in,
                              void* d_out, int out_size, void* d_ws, size_t ws_size,
                              hipStream_t stream) {
  const float* x  = (const float*)d_in[0];
  const float* Wq = (const float*)d_in[1];
  const float* bq = (const float*)d_in[2];
  const float* Wk = (const float*)d_in[3];
  const float* bk = (const float*)d_in[4];
  const float* W0 = (const float*)d_in[5];
  const float* b0 = (const float*)d_in[6];
  float* out = (float*)d_out;

  char* ws = (char*)d_ws;
  u16* xb  = (u16*)(ws + 0);          // 8 MB
  u16* wqT = (u16*)(ws + 8388608);    // 2 MB  [wqT|wkT] adjacent = [2048][1024]
  u16* wkT = (u16*)(ws + 10485760);   // 2 MB
  u16* w0T = (u16*)(ws + 12582912);   // 2 MB
  u16* q   = (u16*)(ws + 14680064);   // 8 MB  [BH][S][64]
  u16* k   = (u16*)(ws + 23068672);   // 8 MB  (pre-scaled by 0.125*log2e)
  u16* qT  = (u16*)(ws + 31457280);   // 8 MB  [BH][64][S]
  u16* att = (u16*)(ws + 39845888);   // 8 MB  [B][S][D]

  prep_kernel<<<dim3(1792), dim3(256), 0, stream>>>(x, xb, Wq, Wk, W0, wqT, wkT, w0T);
  // fused Q+K projection: N=2048 over [wqT|wkT]; writes q, k(prescaled)
  gemm_kernel<0, 16><<<dim3(512), dim3(512), 0, stream>>>(xb, wqT, bq, bk, q, k, nullptr);
  transpose_q_kernel<<<dim3(32, 32), dim3(256), 0, stream>>>(q, qT);
  attn_kernel<<<dim3(1024), dim3(256), 0, stream>>>(q, k, qT, att);
  gemm_kernel<2, 8><<<dim3(256), dim3(512), 0, stream>>>(att, w0T, b0, nullptr, nullptr, nullptr, out);
}

// Round 11
// 175.990 us; speedup vs baseline: 1.0369x; 1.0369x over previous
//
#include <hip/hip_runtime.h>
#include <cstdint>
#include <cstddef>

// MHA fused pipeline for B=2,S=2048,D=1024,H=16,DK=64 on gfx950.
// bf16 MFMA (16x16x32) with fp32 accum; V = Q (reference bug replicated).
// R11: bisect R10's failure. KEEP ones-MFMA denominator (algebraically exact
// colsum of the same P fragments PV consumes). REVERT cvt_pk inline asm and
// __builtin_amdgcn_exp2f back to R6-proven pk2bf + exp2f (prime suspects).

#define AS1 __attribute__((address_space(1)))
#define AS3 __attribute__((address_space(3)))

typedef unsigned short u16;
typedef __attribute__((ext_vector_type(8))) short bf16x8;  // 8 bf16 (4 VGPRs)
typedef __attribute__((ext_vector_type(4))) float f32x4;

__device__ __forceinline__ u16 f2bf(float f) {
  uint32_t u = __builtin_bit_cast(uint32_t, f);
  u += 0x7fffu + ((u >> 16) & 1u);   // RNE
  return (u16)(u >> 16);
}
__device__ __forceinline__ uint32_t pk2bf(float a, float b) {
  return (uint32_t)f2bf(a) | ((uint32_t)f2bf(b) << 16);
}

// async global->LDS, 16B per lane. LDS dest is wave-uniform base + lane*16.
__device__ __forceinline__ void gload16(const void* g, void* l) {
  __builtin_amdgcn_global_load_lds((const AS1 uint32_t*)(uintptr_t)g,
                                   (AS3 uint32_t*)(uintptr_t)l, 16, 0, 0);
}

#define SCALE2 0.18033688011112042f   // (1/8) * log2(e)

// ------- prep: cvt x (blocks 0..1023) + transpose weights (blocks 1024..1791) ----
__global__ __launch_bounds__(256) void prep_kernel(
    const float* __restrict__ x, u16* __restrict__ xb,
    const float* __restrict__ Wq, const float* __restrict__ Wk,
    const float* __restrict__ W0, u16* __restrict__ wqT,
    u16* __restrict__ wkT, u16* __restrict__ w0T) {
  __shared__ u16 T[64][65];
  const int bid = blockIdx.x;
  if (bid < 1024) {
    const float4* x4 = (const float4*)x;
    ushort4* o4 = (ushort4*)xb;
    for (int i = bid * 256 + threadIdx.x; i < 1048576; i += 262144) {
      float4 v = x4[i];
      ushort4 o;
      o.x = f2bf(v.x); o.y = f2bf(v.y); o.z = f2bf(v.z); o.w = f2bf(v.w);
      o4[i] = o;
    }
    return;
  }
  const int t = bid - 1024;
  const int z = t >> 8, y = (t >> 4) & 15, xt = t & 15;
  const float* src; u16* dst;
  if (z == 0)      { src = Wq; dst = wqT; }
  else if (z == 1) { src = Wk; dst = wkT; }
  else             { src = W0; dst = w0T; }
  const int k0 = y * 64, n0 = xt * 64;
  const int c = threadIdx.x & 63, r0 = threadIdx.x >> 6;
#pragma unroll
  for (int i = 0; i < 16; ++i) {
    int r = i * 4 + r0;
    T[r][c] = f2bf(src[(size_t)(k0 + r) * 1024 + n0 + c]);
  }
  __syncthreads();
#pragma unroll
  for (int i = 0; i < 16; ++i) {
    int r = i * 4 + r0;
    dst[(size_t)(n0 + r) * 1024 + k0 + c] = T[c][r];  // WT[n][k] = W[k][n]
  }
}

// ------- transpose q: [BH][S][64] -> qT [BH][64][S] (bf16, LDS-tiled) -------
__global__ __launch_bounds__(256) void transpose_q_kernel(const u16* __restrict__ q,
                                                          u16* __restrict__ qT) {
  const int bh = blockIdx.y;
  const int s0 = blockIdx.x * 64;
  const u16* src = q + (size_t)bh * 2048 * 64;
  u16* dst = qT + (size_t)bh * 64 * 2048;
  __shared__ u16 T[64][65];
  const int c = threadIdx.x & 63, r0 = threadIdx.x >> 6;
#pragma unroll
  for (int i = 0; i < 16; ++i) {
    int r = i * 4 + r0;
    T[r][c] = src[(size_t)(s0 + r) * 64 + c];
  }
  __syncthreads();
#pragma unroll
  for (int i = 0; i < 16; ++i) {
    int r = i * 4 + r0;
    dst[(size_t)r * 2048 + s0 + c] = T[c][r];  // qT[d][s] = q[s][d]
  }
}

// ------- GEMM: C[4096][N] = A @ BT^T + bias. 128x128 tile, 8 waves, BK=64. ----
// EPI 0 (fused QK proj, NTILES=16): n<1024 -> q (bf16 head layout, +bq);
//   n>=1024 -> k (bf16 head layout, (acc+bk)*SCALE2 pre-scaled).
// EPI 2 (out proj, NTILES=8): fp32 row-major +bias0.
template <int EPI, int NTILES>
__global__ __launch_bounds__(512, 4) void gemm_kernel(
    const u16* __restrict__ A, const u16* __restrict__ BT,
    const float* __restrict__ bias0, const float* __restrict__ bias1,
    u16* __restrict__ Oq, u16* __restrict__ Ok, float* __restrict__ Of) {
  __shared__ __align__(16) u16 As[128][64];
  __shared__ __align__(16) u16 Bs[128][64];
  const int tid = threadIdx.x, wid = tid >> 6, lane = tid & 63;
  const int l15 = lane & 15, lg = lane >> 4;
  constexpr int NH = NTILES / 2;
  const int bid = blockIdx.x;
  const int c = bid & 7, l = bid >> 3;
  const int m0 = ((c >> 1) * 8 + l / NH) * 128;
  const int n0 = ((c & 1) * NH + l % NH) * 128;
  const int wrow = (wid >> 2) * 64, wcol = (wid & 3) * 32;
  const int srow = lane >> 3;
  const int gz = ((lane & 7) ^ srow) * 8;   // pre-swizzled global col (u16)

  f32x4 acc[4][2] = {};

  for (int k0 = 0; k0 < 1024; k0 += 64) {
#pragma unroll
    for (int i = 0; i < 2; ++i) {
      int ch = wid * 2 + i;  // 16 chunks of 8 rows each, for both tiles
      gload16(&A[(size_t)(m0 + ch * 8 + srow) * 1024 + k0 + gz], &As[ch * 8][0]);
      gload16(&BT[(size_t)(n0 + ch * 8 + srow) * 1024 + k0 + gz], &Bs[ch * 8][0]);
    }
    __syncthreads();
#pragma unroll
    for (int kf = 0; kf < 2; ++kf) {
      const int cg = ((kf * 4 + lg) ^ (lane & 7)) * 8;  // swizzled read granule
      bf16x8 af[4], bfr[2];
#pragma unroll
      for (int m = 0; m < 4; ++m)
        af[m] = *(const bf16x8*)&As[wrow + m * 16 + l15][cg];
#pragma unroll
      for (int n = 0; n < 2; ++n)
        bfr[n] = *(const bf16x8*)&Bs[wcol + n * 16 + l15][cg];
#pragma unroll
      for (int m = 0; m < 4; ++m)
#pragma unroll
        for (int n = 0; n < 2; ++n)
          acc[m][n] = __builtin_amdgcn_mfma_f32_16x16x32_bf16(af[m], bfr[n], acc[m][n], 0, 0, 0);
    }
    __syncthreads();
  }

  // epilogue
  const bool isq = (n0 < 1024);  // block-uniform (tiles are 128-wide)
  float bv[2];
#pragma unroll
  for (int n = 0; n < 2; ++n) {
    const int gn = n0 + wcol + n * 16 + l15;
    if constexpr (EPI == 0)
      bv[n] = isq ? bias0[gn] : bias1[gn - 1024];
    else
      bv[n] = bias0[gn];
  }
#pragma unroll
  for (int m = 0; m < 4; ++m) {
#pragma unroll
    for (int r = 0; r < 4; ++r) {
      const int gm = m0 + wrow + m * 16 + lg * 4 + r;
#pragma unroll
      for (int n = 0; n < 2; ++n) {
        const int gn = n0 + wcol + n * 16 + l15;
        float v = acc[m][n][r] + bv[n];
        if constexpr (EPI == 2) {
          Of[(size_t)gm * 1024 + gn] = v;
        } else {
          const int gg = gn & 1023;
          const int b = gm >> 11, s = gm & 2047;
          const int h = gg >> 6, dk = gg & 63;
          const size_t bh = (size_t)(b * 16 + h);
          if (isq) {
            Oq[(bh * 2048 + s) * 64 + dk] = f2bf(v);
          } else {
            Ok[(bh * 2048 + s) * 64 + dk] = f2bf(v * SCALE2);  // pre-scaled K
          }
        }
      }
    }
  }
}

// ---------------- flash attention, causal, V = Q, swapped QK^T ----------------
// 1024 blocks (1 q-tile each), heavy-first; bh = bid&31 -> XCD-affine.
// 4 waves x 16 q-rows. Each lane owns q-row l15: S^T accum has kv lane-local.
// Softmax denominator accumulated by ones-MFMA (row-sum on the matrix pipe).
__global__ __launch_bounds__(256, 4) void attn_kernel(const u16* __restrict__ Q,
                                                      const u16* __restrict__ K,
                                                      const u16* __restrict__ QT,
                                                      u16* __restrict__ ATT) {
  __shared__ __align__(16) u16 Ks[2][64][64];    // K tile  [kv][dk]   (swizzled)
  __shared__ __align__(16) u16 Vs[2][64][64];    // V^T tile [dk][kv]  (swizzled)
  __shared__ __align__(16) u16 Ps[4][16][64];    // per-wave P [q][kv] (swizzled)
  const int tid = threadIdx.x, wid = tid >> 6, lane = tid & 63;
  const int l15 = lane & 15, lg = lane >> 4;
  const int bid = blockIdx.x;
  const int bh = bid & 31;              // bid%8 spreads bh across XCDs
  const int qt = 31 - (bid >> 5);       // heavy tiles dispatched first
  const size_t base = (size_t)bh * 2048 * 64;
  const int bb = bh >> 4, hh = bh & 15;
  const int srow = lane >> 3;
  const int gz = ((lane & 7) ^ srow) * 8;

  const int q0 = qt * 64;
  const int wrow = q0 + wid * 16;

  // hoisted staging pointers (this thread's two chunk rows of each tile)
  const u16* kA  = K  + base + (size_t)(wid * 16 + srow) * 64 + gz;        // +t*4096
  const u16* kB  = kA + 8 * 64;
  const u16* vA  = QT + base + (size_t)(wid * 16 + srow) * 2048 + gz;      // +t*64
  const u16* vB  = vA + 8 * 2048;
  u16* ldsKA = &Ks[0][wid * 16][0];      // buffer stride = 64*64 u16
  u16* ldsKB = &Ks[0][wid * 16 + 8][0];
  u16* ldsVA = &Vs[0][wid * 16][0];
  u16* ldsVB = &Vs[0][wid * 16 + 8][0];
  const int bufo = 64 * 64;              // u16 per buffer

  bf16x8 qf[2];   // Q rows for this wave: row = wrow + l15 (B-operand fragment)
#pragma unroll
  for (int kf = 0; kf < 2; ++kf)
    qf[kf] = *(const bf16x8*)&Q[base + (size_t)(wrow + l15) * 64 + kf * 32 + lg * 8];

  bf16x8 onesf;   // A-fragment of all-1.0 bf16: row-sum MFMA operand
#pragma unroll
  for (int i = 0; i < 8; ++i) onesf[i] = (short)0x3F80;

  f32x4 o[4] = {};          // O^T accum: o[m][r] = O^T[d=m*16+lg*4+r][q=l15]
  f32x4 sma = {};           // ones-MFMA accum: every entry = sum_kv P[q=l15][kv]
  float mx = -3e38f;

  // prologue: stage tile 0 into buffer 0
  gload16(kA, ldsKA); gload16(kB, ldsKB);
  gload16(vA, ldsVA); gload16(vB, ldsVB);
  __syncthreads();

  for (int t = 0; t <= qt; ++t) {
    const int cur = t & 1;
    if (t < qt) {           // prefetch next tile into the other buffer
      const int nxt = (cur ^ 1) * bufo;
      gload16(kA + (t + 1) * 4096, ldsKA + nxt);
      gload16(kB + (t + 1) * 4096, ldsKB + nxt);
      gload16(vA + (t + 1) * 64,   ldsVA + nxt);
      gload16(vB + (t + 1) * 64,   ldsVB + nxt);
    }

    // S^T = K Q^T  (rows kv = n*16+lg*4+r, cols q = l15). K pre-scaled to log2.
    f32x4 sc[4] = {};
#pragma unroll
    for (int kf = 0; kf < 2; ++kf) {
      const int cg = ((kf * 4 + lg) ^ (lane & 7)) * 8;
      bf16x8 kb[4];
#pragma unroll
      for (int n = 0; n < 4; ++n)
        kb[n] = *(const bf16x8*)&Ks[cur][n * 16 + l15][cg];
      __builtin_amdgcn_s_setprio(1);
#pragma unroll
      for (int n = 0; n < 4; ++n)
        sc[n] = __builtin_amdgcn_mfma_f32_16x16x32_bf16(kb[n], qf[kf], sc[n], 0, 0, 0);
      __builtin_amdgcn_s_setprio(0);
    }

    // causal mask on diagonal tile: kv (= n*16+lg*4+r) > q (= wid*16+l15)
    if (t == qt) {
      const int qq = wid * 16 + l15;
#pragma unroll
      for (int n = 0; n < 4; ++n)
#pragma unroll
        for (int r = 0; r < 4; ++r)
          if (n * 16 + lg * 4 + r > qq) sc[n][r] = -1e30f;
    }

    // row max: in-register tree over this lane's 16 kv values + 2 shfl (lg groups)
    float ma = fmaxf(fmaxf(sc[0][0], sc[0][1]), fmaxf(sc[0][2], sc[0][3]));
    float mb = fmaxf(fmaxf(sc[1][0], sc[1][1]), fmaxf(sc[1][2], sc[1][3]));
    float mc = fmaxf(fmaxf(sc[2][0], sc[2][1]), fmaxf(sc[2][2], sc[2][3]));
    float md = fmaxf(fmaxf(sc[3][0], sc[3][1]), fmaxf(sc[3][2], sc[3][3]));
    float rmax = fmaxf(fmaxf(ma, mb), fmaxf(mc, md));
    rmax = fmaxf(rmax, __shfl_xor(rmax, 16));
    rmax = fmaxf(rmax, __shfl_xor(rmax, 32));

    // defer-max (T13): rescale only when max grew by >8 (log2 units)
    if (__any(rmax > mx + 8.0f)) {
      const float mnew = fmaxf(mx, rmax);
      const float alpha = exp2f(mx - mnew);
      mx = mnew;
      sma *= alpha;
#pragma unroll
      for (int m = 0; m < 4; ++m) o[m] *= alpha;
    }

    // exp2 and pack to bf16 (R6-proven integer pack; sum via ones-MFMA below)
    uint32_t w[4][2];
#pragma unroll
    for (int n = 0; n < 4; ++n) {
      const float p0 = exp2f(sc[n][0] - mx), p1 = exp2f(sc[n][1] - mx);
      const float p2 = exp2f(sc[n][2] - mx), p3 = exp2f(sc[n][3] - mx);
      w[n][0] = pk2bf(p0, p1);
      w[n][1] = pk2bf(p2, p3);
    }

    // P -> LDS as [q=l15][kv], kv-run of 4 per store -> ds_write_b64, swizzled
#pragma unroll
    for (int n = 0; n < 4; ++n) {
      const int col = (((2 * n + (lg >> 1)) ^ (l15 & 7)) << 3) + ((lg & 1) << 2);
      uint2 wv; wv.x = w[n][0]; wv.y = w[n][1];
      *(uint2*)&Ps[wid][l15][col] = wv;
    }
    asm volatile("s_waitcnt lgkmcnt(0)" ::: "memory");

    // O^T += V^T P^T ; denominator += ones * P^T  (all on the matrix pipe)
#pragma unroll
    for (int kf = 0; kf < 2; ++kf) {
      const int cg = ((kf * 4 + lg) ^ (lane & 7)) * 8;
      bf16x8 pb = *(const bf16x8*)&Ps[wid][l15][cg];
      bf16x8 vb[4];
#pragma unroll
      for (int m = 0; m < 4; ++m)
        vb[m] = *(const bf16x8*)&Vs[cur][m * 16 + l15][cg];
      __builtin_amdgcn_s_setprio(1);
#pragma unroll
      for (int m = 0; m < 4; ++m)
        o[m] = __builtin_amdgcn_mfma_f32_16x16x32_bf16(vb[m], pb, o[m], 0, 0, 0);
      sma = __builtin_amdgcn_mfma_f32_16x16x32_bf16(onesf, pb, sma, 0, 0, 0);
      __builtin_amdgcn_s_setprio(0);
    }
    __syncthreads();   // drains prefetch vmcnt + LDS; next iter reads other buffer
  }

  // denominator: every row of the ones-MFMA output equals sum_kv P[l15][kv]
  const float inv = 1.0f / sma[0];
  const int s = wrow + l15;
#pragma unroll
  for (int m = 0; m < 4; ++m) {
    uint2 wv;
    wv.x = pk2bf(o[m][0] * inv, o[m][1] * inv);
    wv.y = pk2bf(o[m][2] * inv, o[m][3] * inv);
    *(uint2*)&ATT[((size_t)(bb * 2048 + s)) * 1024 + hh * 64 + m * 16 + lg * 4] = wv;
  }
}

// ---------------- launcher ----------------
extern "C" void kernel_launch(void* const* d_in, const int* in_sizes, int n_in,
                              void* d_out, int out_size, void* d_ws, size_t ws_size,
                              hipStream_t stream) {
  const float* x  = (const float*)d_in[0];
  const float* Wq = (const float*)d_in[1];
  const float* bq = (const float*)d_in[2];
  const float* Wk = (const float*)d_in[3];
  const float* bk = (const float*)d_in[4];
  const float* W0 = (const float*)d_in[5];
  const float* b0 = (const float*)d_in[6];
  float* out = (float*)d_out;

  char* ws = (char*)d_ws;
  u16* xb  = (u16*)(ws + 0);          // 8 MB
  u16* wqT = (u16*)(ws + 8388608);    // 2 MB  [wqT|wkT] adjacent = [2048][1024]
  u16* wkT = (u16*)(ws + 10485760);   // 2 MB
  u16* w0T = (u16*)(ws + 12582912);   // 2 MB
  u16* q   = (u16*)(ws + 14680064);   // 8 MB  [BH][S][64]
  u16* k   = (u16*)(ws + 23068672);   // 8 MB  (pre-scaled by 0.125*log2e)
  u16* qT  = (u16*)(ws + 31457280);   // 8 MB  [BH][64][S]
  u16* att = (u16*)(ws + 39845888);   // 8 MB  [B][S][D]

  prep_kernel<<<dim3(1792), dim3(256), 0, stream>>>(x, xb, Wq, Wk, W0, wqT, wkT, w0T);
  // fused Q+K projection: N=2048 over [wqT|wkT]; writes q, k(prescaled)
  gemm_kernel<0, 16><<<dim3(512), dim3(512), 0, stream>>>(xb, wqT, bq, bk, q, k, nullptr);
  transpose_q_kernel<<<dim3(32, 32), dim3(256), 0, stream>>>(q, qT);
  attn_kernel<<<dim3(1024), dim3(256), 0, stream>>>(q, k, qT, att);
  gemm_kernel<2, 8><<<dim3(256), dim3(512), 0, stream>>>(att, w0T, b0, nullptr, nullptr, nullptr, out);
}